// Round 3
// baseline (173.612 us; speedup 1.0000x reference)
//
#include <hip/hip_runtime.h>
#include <math.h>

#define NPTS 4096
#define KNN  20
#define NOUT 64
#define WPB  2               // waves per block (barrier-free; packaging only)
#define QPW  4               // queries per wave
#define QBLK (WPB * QPW)     // 8 queries per block
#define BLKT (WPB * 64)      // 128 threads
#define PCAP 128             // per-query pool capacity == selection capacity
#define NPAIR (NPTS / 2)     // 2048 candidate pairs per batch

typedef float f32x2 __attribute__((ext_vector_type(2)));

// monotone float->uint map (total order preserved)
__device__ __forceinline__ unsigned ord32(float f) {
    unsigned u = __float_as_uint(f);
    int m = ((int)u) >> 31;
    return u ^ ((unsigned)m | 0x80000000u);
}
// inverse of ord32
__device__ __forceinline__ float iord32(unsigned r) {
    unsigned u = (r & 0x80000000u) ? (r ^ 0x80000000u) : ~r;
    return __uint_as_float(u);
}
__device__ __forceinline__ int mbcnt64(unsigned long long m) {
    return __builtin_amdgcn_mbcnt_hi((unsigned)(m >> 32),
           __builtin_amdgcn_mbcnt_lo((unsigned)m, 0));
}
// packed 2xf32 fma -> v_pk_fma_f32 on gfx950 (FeaturePackedFP32Ops)
__device__ __forceinline__ f32x2 pkfma(f32x2 a, f32x2 b, f32x2 c) {
    return __builtin_elementwise_fma(a, b, c);
}

// prologue: pair-packed planes per batch (4096 float4 per batch):
//   A[j] = (x_{2j}, x_{2j+1}, y_{2j}, y_{2j+1})            j in [0, 2048)
//   B[j] = (z_{2j}, z_{2j+1}, w_{2j}, w_{2j+1}),  w = -(x^2+y^2+z^2)
__global__ __launch_bounds__(256) void pack_kernel(const float* __restrict__ x,
                                                   float4* __restrict__ xq) {
    const int i = blockIdx.x * 256 + threadIdx.x;   // over B*NPAIR pairs
    const int b = i >> 11, j = i & (NPAIR - 1);
    const float* xb = x + (size_t)b * 3 * NPTS;
    const f32x2 xx = *(const f32x2*)(xb + 2 * j);
    const f32x2 yy = *(const f32x2*)(xb + NPTS + 2 * j);
    const f32x2 zz = *(const f32x2*)(xb + 2 * NPTS + 2 * j);
    const float w0 = -fmaf(xx.x, xx.x, fmaf(yy.x, yy.x, zz.x * zz.x));
    const float w1 = -fmaf(xx.y, xx.y, fmaf(yy.y, yy.y, zz.y * zz.y));
    float4* dst = xq + (size_t)b * (2 * NPAIR);
    dst[j]         = make_float4(xx.x, xx.y, yy.x, yy.y);   // A-plane
    dst[NPAIR + j] = make_float4(zz.x, zz.y, w0, w1);       // B-plane
}

__global__ __launch_bounds__(BLKT, 6) void edgeconv_kernel(
    const float4* __restrict__ xq,    // (B, 2*NPAIR) pair-packed planes
    const float* __restrict__ Wm,     // (64, 6)
    const float* __restrict__ gamma,
    const float* __restrict__ beta,
    const float* __restrict__ mean,
    const float* __restrict__ var,
    float* __restrict__ out)          // (B, 64, N)
{
    const int bid = blockIdx.x;
    const int b   = bid >> 9;                    // 512 blocks per batch
    const int n0  = (bid & 511) * QBLK;
    const int t    = threadIdx.x;
    const int lane = t & 63;
    const int w    = t >> 6;

    __shared__ unsigned long long pool[QBLK * PCAP];    // 8 KB, wave-private rows
    __shared__ int cnt[QBLK];

    const float4* Ab = xq + (size_t)b * (2 * NPAIR);
    const float4* Bb = Ab + NPAIR;

    // own wave's counters only; same-wave DS ops are in-order -> no barrier
    if (lane < QPW) cnt[QPW * w + lane] = 0;

    // ---- query constants (uniform -> scalar loads) ----
    const int na = __builtin_amdgcn_readfirstlane(n0 + QPW * w);
    const float4 A0 = Ab[na / 2], A1 = Ab[na / 2 + 1];
    const float4 B0 = Bb[na / 2], B1 = Bb[na / 2 + 1];
    // query q = point na+q:  q0=2x, q1=2y, q2=2z  (uniform scalars)
    const float q0s[QPW] = {2.f * A0.x, 2.f * A0.y, 2.f * A1.x, 2.f * A1.y};
    const float q1s[QPW] = {2.f * A0.z, 2.f * A0.w, 2.f * A1.z, 2.f * A1.w};
    const float q2s[QPW] = {2.f * B0.x, 2.f * B0.y, 2.f * B1.x, 2.f * B1.y};
    f32x2 Q0[QPW], Q1[QPW], Q2[QPW];
    #pragma unroll
    for (int q = 0; q < QPW; ++q) {
        Q0[q] = (f32x2){q0s[q], q0s[q]};
        Q1[q] = (f32x2){q1s[q], q1s[q]};
        Q2[q] = (f32x2){q2s[q], q2s[q]};
    }

    // ---- max pass: first 2048 candidates (1024 pairs), 2 groups per query ----
    // vm0 covers candidates 0..1023, vm1 covers 1024..2047 (packed 2-wide).
    f32x2 vm0[QPW], vm1[QPW];
    #pragma unroll
    for (int q = 0; q < QPW; ++q) {
        vm0[q] = (f32x2){-INFINITY, -INFINITY};
        vm1[q] = (f32x2){-INFINITY, -INFINITY};
    }
    #pragma unroll
    for (int g = 0; g < 4; ++g) {                       // 4 iters of 4 pairs
        float4 av[4], bv[4];
        #pragma unroll
        for (int u = 0; u < 4; ++u) {
            const int pi = (g * 4 + u) * 64 + lane;
            av[u] = Ab[pi]; bv[u] = Bb[pi];
        }
        #pragma unroll
        for (int u = 0; u < 4; ++u) {
            const f32x2 X = {av[u].x, av[u].y}, Y = {av[u].z, av[u].w};
            const f32x2 Z = {bv[u].x, bv[u].y}, Wp = {bv[u].z, bv[u].w};
            #pragma unroll
            for (int q = 0; q < QPW; ++q) {
                const f32x2 e2 = pkfma(Q0[q], X, pkfma(Q1[q], Y, pkfma(Q2[q], Z, Wp)));
                if (g < 2) vm0[q] = __builtin_elementwise_max(vm0[q], e2);
                else       vm1[q] = __builtin_elementwise_max(vm1[q], e2);
            }
        }
    }

    // ---- T[q] ~ 20th-largest of 128 group maxima (16-bit ballot bsearch) ----
    // The 20 top group-maxima are 20 distinct candidates >= T, so the true
    // 20th-best >= T => {all candidates >= T} is a superset of the exact
    // top-20. Partition into groups is arbitrary; guarantee holds regardless.
    // 16-bit truncation only lowers T (safe, slightly larger pool).
    float Tf[QPW];
    #pragma unroll
    for (int q = 0; q < QPW; ++q) {
        const unsigned h0 = ord32(fmaxf(vm0[q].x, vm0[q].y)) >> 16;
        const unsigned h1 = ord32(fmaxf(vm1[q].x, vm1[q].y)) >> 16;
        unsigned K = 0;
        #pragma unroll
        for (int bit = 15; bit >= 0; --bit) {
            const unsigned p = K | (1u << bit);
            const int c = __popcll(__ballot(h0 >= p)) + __popcll(__ballot(h1 >= p));
            if (c >= KNN) K = p;
        }
        Tf[q] = iord32(K << 16);
    }

    const int lane2 = 2 * lane;

    // ---- filter pass: all 4096 candidates (2048 pairs), fused filter+append ----
    #pragma unroll
    for (int g = 0; g < 8; ++g) {                       // 8 iters of 4 pairs
        float4 av[4], bv[4];
        #pragma unroll
        for (int u = 0; u < 4; ++u) {
            const int pi = (g * 4 + u) * 64 + lane;
            av[u] = Ab[pi]; bv[u] = Bb[pi];
        }
        #pragma unroll
        for (int u = 0; u < 4; ++u) {
            const f32x2 X = {av[u].x, av[u].y}, Y = {av[u].z, av[u].w};
            const f32x2 Z = {bv[u].x, bv[u].y}, Wp = {bv[u].z, bv[u].w};
            // candidates c0 = 2*pi, c1 = 2*pi+1; tag = (NPTS-1) - c (descending)
            const int tb = (NPTS - 1) - 2 * ((g * 4 + u) * 64);
            const unsigned tag0 = (unsigned)(tb - lane2);
            #pragma unroll
            for (int q = 0; q < QPW; ++q) {
                const f32x2 e2 = pkfma(Q0[q], X, pkfma(Q1[q], Y, pkfma(Q2[q], Z, Wp)));
                if (e2.x >= Tf[q]) {
                    const int pos = atomicAdd(&cnt[QPW * w + q], 1);
                    if (pos < PCAP)
                        pool[(QPW * w + q) * PCAP + pos] =
                            ((unsigned long long)ord32(e2.x) << 32) | tag0;
                }
                if (e2.y >= Tf[q]) {
                    const int pos = atomicAdd(&cnt[QPW * w + q], 1);
                    if (pos < PCAP)
                        pool[(QPW * w + q) * PCAP + pos] =
                            ((unsigned long long)ord32(e2.y) << 32) | (tag0 - 1);
                }
            }
        }
    }

    // ---- exact top-20 set per query: 32-bit ballot bsearch, 2 entries/lane ----
    // Wave-private pool; same-wave DS ops are in-order -> no barrier needed.
    unsigned myidx[QPW];
    #pragma unroll
    for (int q = 0; q < QPW; ++q) {
        const int pr = QPW * w + q;
        unsigned long long* pl = pool + (size_t)pr * PCAP;
        int cw = __builtin_amdgcn_readfirstlane(cnt[pr]);
        if (cw > PCAP) cw = PCAP;                      // >= 20 guaranteed

        // sentinel 0: ord32(finite) >= 1, so pad entries never counted
        const unsigned long long e0 = (lane < cw) ? pl[lane] : 0ull;
        const unsigned long long e1 = (lane + 64 < cw) ? pl[lane + 64] : 0ull;
        const unsigned k0 = (unsigned)(e0 >> 32), t0 = (unsigned)e0;
        const unsigned k1 = (unsigned)(e1 >> 32), t1 = (unsigned)e1;

        unsigned K = 0;
        #pragma unroll
        for (int bit = 31; bit >= 0; --bit) {
            const unsigned p = K | (1u << bit);
            const int c = __popcll(__ballot(k0 >= p)) + __popcll(__ballot(k1 >= p));
            if (c >= KNN) K = p;
        }

        unsigned long long g0 = __ballot(k0 > K);
        unsigned long long g1 = __ballot(k1 > K);
        const int m = __popcll(g0) + __popcll(g1);     // <= 19
        unsigned long long s0 = __ballot(k0 == K);
        unsigned long long s1 = __ballot(k1 == K);
        const int r = KNN - m;                         // >= 1 ties needed
        if (__popcll(s0) + __popcll(s1) > r) {
            // tie split: choose r ties with largest tag (= lowest index)
            unsigned TT = 0;
            #pragma unroll
            for (int bit = 11; bit >= 0; --bit) {      // tags < 4096
                const unsigned p = TT | (1u << bit);
                const int c = __popcll(__ballot(k0 == K && t0 >= p)) +
                              __popcll(__ballot(k1 == K && t1 >= p));
                if (c >= r) TT = p;
            }
            s0 = __ballot(k0 == K && t0 >= TT);
            s1 = __ballot(k1 == K && t1 >= TT);
        }

        unsigned* idxq = (unsigned*)pl;                // alias own (consumed) pool
        if ((g0 >> lane) & 1) idxq[mbcnt64(g0)] = t0;
        if ((g1 >> lane) & 1) idxq[__popcll(g0) + mbcnt64(g1)] = t1;
        if ((s0 >> lane) & 1) idxq[m + mbcnt64(s0)] = t0;
        if ((s1 >> lane) & 1) idxq[m + __popcll(s0) + mbcnt64(s1)] = t1;
        myidx[q] = idxq[(lane < KNN) ? lane : 0];
    }

    // ---- epilogue: lane = output channel; neighbors via scalar loads ----
    const int o = lane;
    const float iv   = gamma[o] / sqrtf(var[o] + 1e-5f);
    const float bias = beta[o] - mean[o] * iv;
    const float* Wr = Wm + o * 6;
    const float w0p = Wr[0] * iv, w1p = Wr[1] * iv, w2p = Wr[2] * iv;
    const float w3p = Wr[3] * iv, w4p = Wr[4] * iv, w5p = Wr[5] * iv;

    // query coords (uniform, from the pair-packed planes)
    const float pvx[QPW] = {A0.x, A0.y, A1.x, A1.y};
    const float pvy[QPW] = {A0.z, A0.w, A1.z, A1.w};
    const float pvz[QPW] = {B0.x, B0.y, B1.x, B1.y};

    float bests[QPW];
    #pragma unroll
    for (int q = 0; q < QPW; ++q) {
        const float basep = fmaf(w3p, pvx[q], fmaf(w4p, pvy[q], fmaf(w5p, pvz[q], bias)));
        const float base2 = basep - fmaf(w0p, pvx[q], fmaf(w1p, pvy[q], w2p * pvz[q]));
        float best = -INFINITY;
        #pragma unroll
        for (int k = 0; k < KNN; ++k) {
            const int lk = __builtin_amdgcn_readlane((int)myidx[q], k);
            const int gi = __builtin_amdgcn_readfirstlane((NPTS - 1) - lk);
            const int pair = gi >> 1, odd = gi & 1;
            const float4 fa = Ab[pair];                       // s_load_dwordx4
            const f32x2  fz = *(const f32x2*)(Bb + pair);     // s_load_dwordx2
            const float fx = odd ? fa.y : fa.x;               // s_cselect
            const float fy = odd ? fa.w : fa.z;
            const float fzz = odd ? fz.y : fz.x;
            float y = fmaf(w0p, fx, fmaf(w1p, fy, fmaf(w2p, fzz, base2)));
            y = fmaxf(y, 0.2f * y);                           // LeakyReLU
            best = fmaxf(best, y);
        }
        bests[q] = best;
    }

    // ---- direct store: lane o writes its 4 consecutive n's as one float4 ----
    float4 res;
    res.x = bests[0]; res.y = bests[1]; res.z = bests[2]; res.w = bests[3];
    *(float4*)(out + ((size_t)b * NOUT + o) * NPTS + na) = res;
}

extern "C" void kernel_launch(void* const* d_in, const int* in_sizes, int n_in,
                              void* d_out, int out_size, void* d_ws, size_t ws_size,
                              hipStream_t stream) {
    const float* x     = (const float*)d_in[0];
    const float* Wm    = (const float*)d_in[1];
    const float* gamma = (const float*)d_in[2];
    const float* beta  = (const float*)d_in[3];
    const float* mean  = (const float*)d_in[4];
    const float* var   = (const float*)d_in[5];
    float* out = (float*)d_out;
    float4* xq = (float4*)d_ws;                    // B * 4096 float4 = 512 KB

    const int B = in_sizes[0] / (3 * NPTS);        // 8
    pack_kernel<<<B * NPAIR / 256, 256, 0, stream>>>(x, xq);
    const int nblocks = B * (NPTS / QBLK);         // 8 * 512 = 4096
    edgeconv_kernel<<<nblocks, BLKT, 0, stream>>>(xq, Wm, gamma, beta, mean, var, out);
}

// Round 4
// 161.174 us; speedup vs baseline: 1.0772x; 1.0772x over previous
//
#include <hip/hip_runtime.h>
#include <math.h>

#define NPTS 4096
#define KNN  20
#define NOUT 64
#define WPB  2               // waves per block (barrier-free; packaging only)
#define QPW  4               // queries per wave
#define QBLK (WPB * QPW)     // 8 queries per block
#define BLKT (WPB * 64)      // 128 threads
#define PCAP 128             // per-query pool capacity == selection capacity
#define NPAIR (NPTS / 2)     // 2048 candidate pairs per batch

typedef float f32x2 __attribute__((ext_vector_type(2)));

// monotone float->uint map (total order preserved)
__device__ __forceinline__ unsigned ord32(float f) {
    unsigned u = __float_as_uint(f);
    int m = ((int)u) >> 31;
    return u ^ ((unsigned)m | 0x80000000u);
}
// inverse of ord32
__device__ __forceinline__ float iord32(unsigned r) {
    unsigned u = (r & 0x80000000u) ? (r ^ 0x80000000u) : ~r;
    return __uint_as_float(u);
}
__device__ __forceinline__ int mbcnt64(unsigned long long m) {
    return __builtin_amdgcn_mbcnt_hi((unsigned)(m >> 32),
           __builtin_amdgcn_mbcnt_lo((unsigned)m, 0));
}
// packed 2xf32 fma -> v_pk_fma_f32 (gfx90a+ FeaturePackedFP32Ops)
__device__ __forceinline__ f32x2 pkfma(f32x2 a, f32x2 b, f32x2 c) {
    return __builtin_elementwise_fma(a, b, c);
}
__device__ __forceinline__ f32x2 pkmax(f32x2 a, f32x2 b) {
    return __builtin_elementwise_max(a, b);   // scalarizes to 2x v_max_f32 (ok)
}
__device__ __forceinline__ f32x2 splat2(float s) { return (f32x2){s, s}; }

// prologue: pair-packed planes per batch (4096 float4 per batch):
//   A[j] = (x_{2j}, x_{2j+1}, y_{2j}, y_{2j+1})            j in [0, 2048)
//   B[j] = (z_{2j}, z_{2j+1}, w_{2j}, w_{2j+1}),  w = -(x^2+y^2+z^2)
__global__ __launch_bounds__(256) void pack_kernel(const float* __restrict__ x,
                                                   float4* __restrict__ xq) {
    const int i = blockIdx.x * 256 + threadIdx.x;   // over B*NPAIR pairs
    const int b = i >> 11, j = i & (NPAIR - 1);
    const float* xb = x + (size_t)b * 3 * NPTS;
    const f32x2 xx = *(const f32x2*)(xb + 2 * j);
    const f32x2 yy = *(const f32x2*)(xb + NPTS + 2 * j);
    const f32x2 zz = *(const f32x2*)(xb + 2 * NPTS + 2 * j);
    const float w0 = -fmaf(xx.x, xx.x, fmaf(yy.x, yy.x, zz.x * zz.x));
    const float w1 = -fmaf(xx.y, xx.y, fmaf(yy.y, yy.y, zz.y * zz.y));
    float4* dst = xq + (size_t)b * (2 * NPAIR);
    dst[j]         = make_float4(xx.x, xx.y, yy.x, yy.y);   // A-plane
    dst[NPAIR + j] = make_float4(zz.x, zz.y, w0, w1);       // B-plane
}

__global__ __launch_bounds__(BLKT, 8) void edgeconv_kernel(
    const float4* __restrict__ xq,    // (B, 2*NPAIR) pair-packed planes
    const float* __restrict__ Wm,     // (64, 6)
    const float* __restrict__ gamma,
    const float* __restrict__ beta,
    const float* __restrict__ mean,
    const float* __restrict__ var,
    float* __restrict__ out)          // (B, 64, N)
{
    const int bid = blockIdx.x;
    const int b   = bid >> 9;                    // 512 blocks per batch
    const int n0  = (bid & 511) * QBLK;
    const int t    = threadIdx.x;
    const int lane = t & 63;
    const int w    = t >> 6;

    __shared__ unsigned long long pool[QBLK * PCAP];    // 8 KB, wave-private rows
    __shared__ int cnt[QBLK];

    const float4* Ab = xq + (size_t)b * (2 * NPAIR);
    const float4* Bb = Ab + NPAIR;

    // own wave's counters only; same-wave DS ops are in-order -> no barrier
    if (lane < QPW) cnt[QPW * w + lane] = 0;

    // ---- query constants (uniform -> scalar loads; named scalars ONLY) ----
    const int na = __builtin_amdgcn_readfirstlane(n0 + QPW * w);
    const float4 A0 = Ab[na >> 1], A1 = Ab[(na >> 1) + 1];
    const float4 B0 = Bb[na >> 1], B1 = Bb[(na >> 1) + 1];
    // query q = point na+q: coeffs (2x, 2y, 2z) as packed splats
    const f32x2 qX0 = splat2(2.f * A0.x), qX1 = splat2(2.f * A0.y);
    const f32x2 qX2 = splat2(2.f * A1.x), qX3 = splat2(2.f * A1.y);
    const f32x2 qY0 = splat2(2.f * A0.z), qY1 = splat2(2.f * A0.w);
    const f32x2 qY2 = splat2(2.f * A1.z), qY3 = splat2(2.f * A1.w);
    const f32x2 qZ0 = splat2(2.f * B0.x), qZ1 = splat2(2.f * B0.y);
    const f32x2 qZ2 = splat2(2.f * B1.x), qZ3 = splat2(2.f * B1.y);

    auto evalq = [](f32x2 Cx, f32x2 Cy, f32x2 Cz, f32x2 Cw,
                    f32x2 sx, f32x2 sy, f32x2 sz) -> f32x2 {
        return pkfma(Cx, sx, pkfma(Cy, sy, pkfma(Cz, sz, Cw)));
    };

    // ---- max pass: first 2048 candidates (1024 pairs), 2 groups per query ----
    // Named f32x2 accumulators (no arrays -> no alloca risk).
    f32x2 vA0 = splat2(-INFINITY); f32x2 vA1 = vA0, vA2 = vA0, vA3 = vA0;
    f32x2 vB0 = vA0, vB1 = vA0, vB2 = vA0, vB3 = vA0;
    #pragma unroll
    for (int g = 0; g < 8; ++g) {                       // 2 pairs per iter
        float4 av[2], bv[2];
        #pragma unroll
        for (int u = 0; u < 2; ++u) {
            const int pi = (g * 2 + u) * 64 + lane;
            av[u] = Ab[pi]; bv[u] = Bb[pi];
        }
        #pragma unroll
        for (int u = 0; u < 2; ++u) {
            const f32x2 Cx = {av[u].x, av[u].y}, Cy = {av[u].z, av[u].w};
            const f32x2 Cz = {bv[u].x, bv[u].y}, Cw = {bv[u].z, bv[u].w};
            if (g < 4) {
                vA0 = pkmax(vA0, evalq(Cx, Cy, Cz, Cw, qX0, qY0, qZ0));
                vA1 = pkmax(vA1, evalq(Cx, Cy, Cz, Cw, qX1, qY1, qZ1));
                vA2 = pkmax(vA2, evalq(Cx, Cy, Cz, Cw, qX2, qY2, qZ2));
                vA3 = pkmax(vA3, evalq(Cx, Cy, Cz, Cw, qX3, qY3, qZ3));
            } else {
                vB0 = pkmax(vB0, evalq(Cx, Cy, Cz, Cw, qX0, qY0, qZ0));
                vB1 = pkmax(vB1, evalq(Cx, Cy, Cz, Cw, qX1, qY1, qZ1));
                vB2 = pkmax(vB2, evalq(Cx, Cy, Cz, Cw, qX2, qY2, qZ2));
                vB3 = pkmax(vB3, evalq(Cx, Cy, Cz, Cw, qX3, qY3, qZ3));
            }
        }
    }

    // ---- T[q] ~ 20th-largest of 128 group maxima (16-bit ballot bsearch) ----
    // 128 disjoint groups (64 lanes x 2 halves, each collapsing its own pair
    // slots): top-20 group maxima are 20 distinct candidates >= T, so
    // {candidates >= T} is a superset of the exact top-20. 16-bit truncation
    // only lowers T (safe, slightly larger pool).
    float Tf0, Tf1, Tf2, Tf3;
#define THRESH(vA, vB, TfOut) { \
    const unsigned h0 = ord32(fmaxf((vA).x, (vA).y)) >> 16; \
    const unsigned h1 = ord32(fmaxf((vB).x, (vB).y)) >> 16; \
    unsigned Kx = 0; \
    _Pragma("unroll") \
    for (int bit = 15; bit >= 0; --bit) { \
        const unsigned p = Kx | (1u << bit); \
        const int c = __popcll(__ballot(h0 >= p)) + __popcll(__ballot(h1 >= p)); \
        if (c >= KNN) Kx = p; \
    } \
    TfOut = iord32(Kx << 16); }
    THRESH(vA0, vB0, Tf0)
    THRESH(vA1, vB1, Tf1)
    THRESH(vA2, vB2, Tf2)
    THRESH(vA3, vB3, Tf3)
#undef THRESH

    const int lane2 = 2 * lane;
    const int cr = QPW * w;

    // ---- filter pass: all 4096 candidates (2048 pairs), fused filter+append ----
#define APPEND(ev, Tfq, qi, tagv) \
    if ((ev) >= (Tfq)) { \
        const int pos = atomicAdd(&cnt[cr + (qi)], 1); \
        if (pos < PCAP) \
            pool[(cr + (qi)) * PCAP + pos] = \
                ((unsigned long long)ord32(ev) << 32) | (unsigned)(tagv); \
    }
    #pragma unroll
    for (int g = 0; g < 16; ++g) {                      // 2 pairs per iter
        float4 av[2], bv[2];
        #pragma unroll
        for (int u = 0; u < 2; ++u) {
            const int pi = (g * 2 + u) * 64 + lane;
            av[u] = Ab[pi]; bv[u] = Bb[pi];
        }
        #pragma unroll
        for (int u = 0; u < 2; ++u) {
            const f32x2 Cx = {av[u].x, av[u].y}, Cy = {av[u].z, av[u].w};
            const f32x2 Cz = {bv[u].x, bv[u].y}, Cw = {bv[u].z, bv[u].w};
            // candidates 2*pi, 2*pi+1; tag = (NPTS-1) - c (descending in c)
            const int tag0 = 4095 - (g * 2 + u) * 128 - lane2;
            const f32x2 e0 = evalq(Cx, Cy, Cz, Cw, qX0, qY0, qZ0);
            const f32x2 e1 = evalq(Cx, Cy, Cz, Cw, qX1, qY1, qZ1);
            const f32x2 e2 = evalq(Cx, Cy, Cz, Cw, qX2, qY2, qZ2);
            const f32x2 e3 = evalq(Cx, Cy, Cz, Cw, qX3, qY3, qZ3);
            APPEND(e0.x, Tf0, 0, tag0)     APPEND(e0.y, Tf0, 0, tag0 - 1)
            APPEND(e1.x, Tf1, 1, tag0)     APPEND(e1.y, Tf1, 1, tag0 - 1)
            APPEND(e2.x, Tf2, 2, tag0)     APPEND(e2.y, Tf2, 2, tag0 - 1)
            APPEND(e3.x, Tf3, 3, tag0)     APPEND(e3.y, Tf3, 3, tag0 - 1)
        }
    }
#undef APPEND

    // ---- exact top-20 set per query: 32-bit ballot bsearch, 2 entries/lane ----
    // Wave-private pool; same-wave DS ops are in-order -> no barrier needed.
    unsigned myidx[QPW];
    #pragma unroll
    for (int q = 0; q < QPW; ++q) {
        const int pr = cr + q;
        unsigned long long* pl = pool + (size_t)pr * PCAP;
        int cw = __builtin_amdgcn_readfirstlane(cnt[pr]);
        if (cw > PCAP) cw = PCAP;                      // >= 20 guaranteed

        // sentinel 0: ord32(finite) >= 1, so pad entries never counted
        const unsigned long long e0 = (lane < cw) ? pl[lane] : 0ull;
        const unsigned long long e1 = (lane + 64 < cw) ? pl[lane + 64] : 0ull;
        const unsigned k0 = (unsigned)(e0 >> 32), t0 = (unsigned)e0;
        const unsigned k1 = (unsigned)(e1 >> 32), t1 = (unsigned)e1;

        unsigned K = 0;
        #pragma unroll
        for (int bit = 31; bit >= 0; --bit) {
            const unsigned p = K | (1u << bit);
            const int c = __popcll(__ballot(k0 >= p)) + __popcll(__ballot(k1 >= p));
            if (c >= KNN) K = p;
        }

        unsigned long long g0 = __ballot(k0 > K);
        unsigned long long g1 = __ballot(k1 > K);
        const int m = __popcll(g0) + __popcll(g1);     // <= 19
        unsigned long long s0 = __ballot(k0 == K);
        unsigned long long s1 = __ballot(k1 == K);
        const int r = KNN - m;                         // >= 1 ties needed
        if (__popcll(s0) + __popcll(s1) > r) {
            // tie split: choose r ties with largest tag (= lowest index)
            unsigned TT = 0;
            #pragma unroll
            for (int bit = 11; bit >= 0; --bit) {      // tags < 4096
                const unsigned p = TT | (1u << bit);
                const int c = __popcll(__ballot(k0 == K && t0 >= p)) +
                              __popcll(__ballot(k1 == K && t1 >= p));
                if (c >= r) TT = p;
            }
            s0 = __ballot(k0 == K && t0 >= TT);
            s1 = __ballot(k1 == K && t1 >= TT);
        }

        unsigned* idxq = (unsigned*)pl;                // alias own (consumed) pool
        if ((g0 >> lane) & 1) idxq[mbcnt64(g0)] = t0;
        if ((g1 >> lane) & 1) idxq[__popcll(g0) + mbcnt64(g1)] = t1;
        if ((s0 >> lane) & 1) idxq[m + mbcnt64(s0)] = t0;
        if ((s1 >> lane) & 1) idxq[m + __popcll(s0) + mbcnt64(s1)] = t1;
        myidx[q] = idxq[(lane < KNN) ? lane : 0];
    }

    // ---- epilogue: lane = output channel; neighbors via scalar loads ----
    const int o = lane;
    const float iv   = gamma[o] / sqrtf(var[o] + 1e-5f);
    const float bias = beta[o] - mean[o] * iv;
    const float* Wr = Wm + o * 6;
    const float w0p = Wr[0] * iv, w1p = Wr[1] * iv, w2p = Wr[2] * iv;
    const float w3p = Wr[3] * iv, w4p = Wr[4] * iv, w5p = Wr[5] * iv;

    float bests[QPW];
    #pragma unroll
    for (int q = 0; q < QPW; ++q) {
        // query coords: compile-time selects (q is an unrolled constant)
        const float px = (q == 0) ? A0.x : (q == 1) ? A0.y : (q == 2) ? A1.x : A1.y;
        const float py = (q == 0) ? A0.z : (q == 1) ? A0.w : (q == 2) ? A1.z : A1.w;
        const float pz = (q == 0) ? B0.x : (q == 1) ? B0.y : (q == 2) ? B1.x : B1.y;
        const float basep = fmaf(w3p, px, fmaf(w4p, py, fmaf(w5p, pz, bias)));
        const float base2 = basep - fmaf(w0p, px, fmaf(w1p, py, w2p * pz));
        float best = -INFINITY;
        #pragma unroll
        for (int k = 0; k < KNN; ++k) {
            const int lk = __builtin_amdgcn_readlane((int)myidx[q], k);
            const int gi = __builtin_amdgcn_readfirstlane((NPTS - 1) - lk);
            const int pair = gi >> 1, odd = gi & 1;
            const float4 fa = Ab[pair];                       // s_load_dwordx4
            const f32x2  fz = *(const f32x2*)(Bb + pair);     // s_load_dwordx2
            const float fx  = odd ? fa.y : fa.x;              // s_cselect
            const float fy  = odd ? fa.w : fa.z;
            const float fzz = odd ? fz.y : fz.x;
            float y = fmaf(w0p, fx, fmaf(w1p, fy, fmaf(w2p, fzz, base2)));
            y = fmaxf(y, 0.2f * y);                           // LeakyReLU
            best = fmaxf(best, y);
        }
        bests[q] = best;
    }

    // ---- direct store: lane o writes its 4 consecutive n's as one float4 ----
    float4 res;
    res.x = bests[0]; res.y = bests[1]; res.z = bests[2]; res.w = bests[3];
    *(float4*)(out + ((size_t)b * NOUT + o) * NPTS + na) = res;
}

extern "C" void kernel_launch(void* const* d_in, const int* in_sizes, int n_in,
                              void* d_out, int out_size, void* d_ws, size_t ws_size,
                              hipStream_t stream) {
    const float* x     = (const float*)d_in[0];
    const float* Wm    = (const float*)d_in[1];
    const float* gamma = (const float*)d_in[2];
    const float* beta  = (const float*)d_in[3];
    const float* mean  = (const float*)d_in[4];
    const float* var   = (const float*)d_in[5];
    float* out = (float*)d_out;
    float4* xq = (float4*)d_ws;                    // B * 4096 float4 = 512 KB

    const int B = in_sizes[0] / (3 * NPTS);        // 8
    pack_kernel<<<B * NPAIR / 256, 256, 0, stream>>>(x, xq);
    const int nblocks = B * (NPTS / QBLK);         // 8 * 512 = 4096
    edgeconv_kernel<<<nblocks, BLKT, 0, stream>>>(xq, Wm, gamma, beta, mean, var, out);
}

// Round 5
// 144.949 us; speedup vs baseline: 1.1977x; 1.1119x over previous
//
#include <hip/hip_runtime.h>
#include <math.h>

#define NPTS 4096
#define KNN  20
#define NOUT 64
#define WPB  2               // waves per block (barrier-free; packaging only)
#define QPW  4               // queries per wave
#define QBLK (WPB * QPW)     // 8 queries per block
#define BLKT (WPB * 64)      // 128 threads
#define PCAP 128             // per-query pool capacity == selection capacity
#define MITER 8              // max-pass iterations (2048-candidate sample)

// monotone float->uint map (total order preserved)
__device__ __forceinline__ unsigned ord32(float f) {
    unsigned u = __float_as_uint(f);
    int m = ((int)u) >> 31;
    return u ^ ((unsigned)m | 0x80000000u);
}
// inverse of ord32
__device__ __forceinline__ float iord32(unsigned r) {
    unsigned u = (r & 0x80000000u) ? (r ^ 0x80000000u) : ~r;
    return __uint_as_float(u);
}
__device__ __forceinline__ int mbcnt64(unsigned long long m) {
    return __builtin_amdgcn_mbcnt_hi((unsigned)(m >> 32),
           __builtin_amdgcn_mbcnt_lo((unsigned)m, 0));
}

// prologue: xq[b][j] = (x0, x1, x2, -(x0^2+x1^2+x2^2))
__global__ __launch_bounds__(256) void pack_kernel(const float* __restrict__ x,
                                                   float4* __restrict__ xq) {
    const int i = blockIdx.x * 256 + threadIdx.x;   // over B*NPTS
    const int b = i >> 12, j = i & (NPTS - 1);
    const float* xb = x + (size_t)b * 3 * NPTS;
    const float a0 = xb[j], a1 = xb[NPTS + j], a2 = xb[2 * NPTS + j];
    xq[i] = make_float4(a0, a1, a2, -fmaf(a0, a0, fmaf(a1, a1, a2 * a2)));
}

__global__ __launch_bounds__(BLKT, 8) void edgeconv_kernel(
    const float4* __restrict__ xq,    // (B, N) packed points
    const float* __restrict__ Wm,     // (64, 6)
    const float* __restrict__ gamma,
    const float* __restrict__ beta,
    const float* __restrict__ mean,
    const float* __restrict__ var,
    float* __restrict__ out)          // (B, 64, N)
{
    const int bid = blockIdx.x;
    const int b   = bid >> 9;                    // 512 blocks per batch
    const int n0  = (bid & 511) * QBLK;
    const int t    = threadIdx.x;
    const int lane = t & 63;
    const int w    = t >> 6;

    __shared__ unsigned long long pool[QBLK * PCAP];    // 8 KB, wave-private rows
    __shared__ int cnt[QBLK];

    const float4* xqb = xq + (size_t)b * NPTS;

    // own wave's counters only; same-wave DS ops are in-order -> no barrier
    if (lane < QPW) cnt[QPW * w + lane] = 0;

    // ---- query constants (uniform -> scalar loads) ----
    const int na = __builtin_amdgcn_readfirstlane(n0 + QPW * w);
    float q0[QPW], q1[QPW], q2[QPW];
    #pragma unroll
    for (int q = 0; q < QPW; ++q) {
        const float4 pv = xqb[na + q];
        q0[q] = 2.f * pv.x; q1[q] = 2.f * pv.y; q2[q] = 2.f * pv.z;
    }

    // ---- max pass: 2048-candidate sample, 2 lane-maxima groups per query ----
    float vm0[QPW], vm1[QPW];
    #pragma unroll
    for (int q = 0; q < QPW; ++q) { vm0[q] = -INFINITY; vm1[q] = -INFINITY; }
    #pragma unroll
    for (int g = 0; g < MITER; ++g) {                   // 8 iters of 4 loads
        float4 cc[4];
        #pragma unroll
        for (int u = 0; u < 4; ++u) cc[u] = xqb[(g * 4 + u) * 64 + lane];
        #pragma unroll
        for (int u = 0; u < 4; ++u) {
            #pragma unroll
            for (int q = 0; q < QPW; ++q) {
                const float e = fmaf(q0[q], cc[u].x, fmaf(q1[q], cc[u].y, fmaf(q2[q], cc[u].z, cc[u].w)));
                if (g < MITER / 2) vm0[q] = fmaxf(vm0[q], e);
                else               vm1[q] = fmaxf(vm1[q], e);
            }
        }
    }

    // ---- T[q] ~ 20th-largest of 128 group maxima (16-bit ballot bsearch) ----
    // The 20 top group-maxima are 20 distinct candidates >= T, so the true
    // 20th-best >= T => {all candidates >= T} is a superset of the exact
    // top-20. 16-bit truncation only lowers T (safe, slightly larger pool).
    // INTERLEAVED (R1 form, clean precedent): rolled bit loop, 4 queries
    // unrolled inside -> 4 independent ballot chains in flight.
    unsigned h0[QPW], h1[QPW], Kt[QPW];
    #pragma unroll
    for (int q = 0; q < QPW; ++q) {
        h0[q] = ord32(vm0[q]) >> 16;
        h1[q] = ord32(vm1[q]) >> 16;
        Kt[q] = 0;
    }
    #pragma unroll 1
    for (int bit = 15; bit >= 0; --bit) {
        #pragma unroll
        for (int q = 0; q < QPW; ++q) {
            const unsigned p = Kt[q] | (1u << bit);
            const int c = __popcll(__ballot(h0[q] >= p)) + __popcll(__ballot(h1[q] >= p));
            if (c >= KNN) Kt[q] = p;
        }
    }
    float Tf[QPW];
    #pragma unroll
    for (int q = 0; q < QPW; ++q) Tf[q] = iord32(Kt[q] << 16);

    const int invl = (NPTS - 1) - lane;

    // ---- filter pass: all 4096 candidates, fused filter+append ----
    #pragma unroll
    for (int g = 0; g < NPTS / 256; ++g) {              // 16 iters of 4 loads
        float4 cc[4];
        #pragma unroll
        for (int u = 0; u < 4; ++u) cc[u] = xqb[(g * 4 + u) * 64 + lane];
        #pragma unroll
        for (int u = 0; u < 4; ++u) {
            const unsigned tag = (unsigned)(invl - (g * 4 + u) * 64);
            #pragma unroll
            for (int q = 0; q < QPW; ++q) {
                const float e = fmaf(q0[q], cc[u].x, fmaf(q1[q], cc[u].y, fmaf(q2[q], cc[u].z, cc[u].w)));
                if (e >= Tf[q]) {
                    const int pos = atomicAdd(&cnt[QPW * w + q], 1);
                    if (pos < PCAP)
                        pool[(QPW * w + q) * PCAP + pos] =
                            ((unsigned long long)ord32(e) << 32) | tag;
                }
            }
        }
    }

    // ---- exact top-20 set per query: 32-bit ballot bsearch, 2 entries/lane ----
    // Wave-private pool; same-wave DS ops are in-order -> no barrier needed.
    // INTERLEAVED (R1 form): per-q loads, then one rolled bit loop with the
    // 4 query chains unrolled inside.
    unsigned k0[QPW], k1[QPW], t0v[QPW], t1v[QPW], Ks[QPW];
    #pragma unroll
    for (int q = 0; q < QPW; ++q) {
        const int pr = QPW * w + q;
        const unsigned long long* pl = pool + (size_t)pr * PCAP;
        int cw = __builtin_amdgcn_readfirstlane(cnt[pr]);
        if (cw > PCAP) cw = PCAP;                      // >= 20 guaranteed
        // sentinel 0: ord32(finite) >= 1, so pad entries never counted
        const unsigned long long e0 = (lane < cw) ? pl[lane] : 0ull;
        const unsigned long long e1 = (lane + 64 < cw) ? pl[lane + 64] : 0ull;
        k0[q] = (unsigned)(e0 >> 32); t0v[q] = (unsigned)e0;
        k1[q] = (unsigned)(e1 >> 32); t1v[q] = (unsigned)e1;
        Ks[q] = 0;
    }
    #pragma unroll 1
    for (int bit = 31; bit >= 0; --bit) {
        #pragma unroll
        for (int q = 0; q < QPW; ++q) {
            const unsigned p = Ks[q] | (1u << bit);
            const int c = __popcll(__ballot(k0[q] >= p)) + __popcll(__ballot(k1[q] >= p));
            if (c >= KNN) Ks[q] = p;
        }
    }

    unsigned myidx[QPW];
    #pragma unroll
    for (int q = 0; q < QPW; ++q) {
        const unsigned K = Ks[q];
        const unsigned t0 = t0v[q], t1 = t1v[q];
        unsigned long long g0 = __ballot(k0[q] > K);
        unsigned long long g1 = __ballot(k1[q] > K);
        const int m = __popcll(g0) + __popcll(g1);     // <= 19
        unsigned long long s0 = __ballot(k0[q] == K);
        unsigned long long s1 = __ballot(k1[q] == K);
        const int r = KNN - m;                         // >= 1 ties needed
        if (__popcll(s0) + __popcll(s1) > r) {
            // tie split: choose r ties with largest tag (= lowest index)
            unsigned TT = 0;
            #pragma unroll
            for (int bit = 11; bit >= 0; --bit) {      // tags < 4096
                const unsigned p = TT | (1u << bit);
                const int c = __popcll(__ballot(k0[q] == K && t0 >= p)) +
                              __popcll(__ballot(k1[q] == K && t1 >= p));
                if (c >= r) TT = p;
            }
            s0 = __ballot(k0[q] == K && t0 >= TT);
            s1 = __ballot(k1[q] == K && t1 >= TT);
        }

        unsigned* idxq = (unsigned*)(pool + (size_t)(QPW * w + q) * PCAP); // alias own (consumed) pool
        if ((g0 >> lane) & 1) idxq[mbcnt64(g0)] = t0;
        if ((g1 >> lane) & 1) idxq[__popcll(g0) + mbcnt64(g1)] = t1;
        if ((s0 >> lane) & 1) idxq[m + mbcnt64(s0)] = t0;
        if ((s1 >> lane) & 1) idxq[m + __popcll(s0) + mbcnt64(s1)] = t1;
        myidx[q] = idxq[(lane < KNN) ? lane : 0];
    }

    // ---- epilogue: lane = output channel; neighbors via scalar loads ----
    const int o = lane;
    const float iv   = gamma[o] / sqrtf(var[o] + 1e-5f);
    const float bias = beta[o] - mean[o] * iv;
    const float* Wr = Wm + o * 6;
    const float w0p = Wr[0] * iv, w1p = Wr[1] * iv, w2p = Wr[2] * iv;
    const float w3p = Wr[3] * iv, w4p = Wr[4] * iv, w5p = Wr[5] * iv;

    float bests[QPW];
    #pragma unroll
    for (int q = 0; q < QPW; ++q) {
        const float4 pv = xqb[na + q];                 // scalar reload
        const float basep = fmaf(w3p, pv.x, fmaf(w4p, pv.y, fmaf(w5p, pv.z, bias)));
        const float base2 = basep - fmaf(w0p, pv.x, fmaf(w1p, pv.y, w2p * pv.z));
        float best = -INFINITY;
        #pragma unroll
        for (int k = 0; k < KNN; ++k) {
            const int lk = __builtin_amdgcn_readlane((int)myidx[q], k);
            const int gi = __builtin_amdgcn_readfirstlane((NPTS - 1) - lk);
            const float4 f = xqb[gi];                  // s_load_dwordx4
            float y = fmaf(w0p, f.x, fmaf(w1p, f.y, fmaf(w2p, f.z, base2)));
            y = fmaxf(y, 0.2f * y);                    // LeakyReLU
            best = fmaxf(best, y);
        }
        bests[q] = best;
    }

    // ---- direct store: lane o writes its 4 consecutive n's as one float4 ----
    float4 res;
    res.x = bests[0]; res.y = bests[1]; res.z = bests[2]; res.w = bests[3];
    *(float4*)(out + ((size_t)b * NOUT + o) * NPTS + na) = res;
}

extern "C" void kernel_launch(void* const* d_in, const int* in_sizes, int n_in,
                              void* d_out, int out_size, void* d_ws, size_t ws_size,
                              hipStream_t stream) {
    const float* x     = (const float*)d_in[0];
    const float* Wm    = (const float*)d_in[1];
    const float* gamma = (const float*)d_in[2];
    const float* beta  = (const float*)d_in[3];
    const float* mean  = (const float*)d_in[4];
    const float* var   = (const float*)d_in[5];
    float* out = (float*)d_out;
    float4* xq = (float4*)d_ws;                    // B*NPTS float4 = 512 KB

    const int B = in_sizes[0] / (3 * NPTS);        // 8
    pack_kernel<<<B * NPTS / 256, 256, 0, stream>>>(x, xq);
    const int nblocks = B * (NPTS / QBLK);         // 8 * 512 = 4096
    edgeconv_kernel<<<nblocks, BLKT, 0, stream>>>(xq, Wm, gamma, beta, mean, var, out);
}

// Round 6
// 142.586 us; speedup vs baseline: 1.2176x; 1.0166x over previous
//
#include <hip/hip_runtime.h>
#include <math.h>

#define NPTS 4096
#define KNN  20
#define NOUT 64
#define WPB  2               // waves per block (barrier-free; packaging only)
#define QPW  4               // queries per wave
#define QBLK (WPB * QPW)     // 8 queries per block
#define BLKT (WPB * 64)      // 128 threads
#define PCAP 128             // per-query pool capacity == selection capacity
#define MITER 8              // max-pass iterations (2048-candidate sample)

// monotone float->uint map (total order preserved)
__device__ __forceinline__ unsigned ord32(float f) {
    unsigned u = __float_as_uint(f);
    int m = ((int)u) >> 31;
    return u ^ ((unsigned)m | 0x80000000u);
}
// inverse of ord32
__device__ __forceinline__ float iord32(unsigned r) {
    unsigned u = (r & 0x80000000u) ? (r ^ 0x80000000u) : ~r;
    return __uint_as_float(u);
}
__device__ __forceinline__ int mbcnt64(unsigned long long m) {
    return __builtin_amdgcn_mbcnt_hi((unsigned)(m >> 32),
           __builtin_amdgcn_mbcnt_lo((unsigned)m, 0));
}

// prologue: xq[b][j] = (x0, x1, x2, -(x0^2+x1^2+x2^2))
__global__ __launch_bounds__(256) void pack_kernel(const float* __restrict__ x,
                                                   float4* __restrict__ xq) {
    const int i = blockIdx.x * 256 + threadIdx.x;   // over B*NPTS
    const int b = i >> 12, j = i & (NPTS - 1);
    const float* xb = x + (size_t)b * 3 * NPTS;
    const float a0 = xb[j], a1 = xb[NPTS + j], a2 = xb[2 * NPTS + j];
    xq[i] = make_float4(a0, a1, a2, -fmaf(a0, a0, fmaf(a1, a1, a2 * a2)));
}

// launch_bounds(BLKT, 4): VGPR cap 128 (was 8 -> cap 64). The 64-cap forced
// whole-array spills to scratch in R2-R5 (WRITE_SIZE 86-130 MB). If the
// kernel still fits <=64 VGPRs it runs 8 waves/EU regardless of this arg.
__global__ __launch_bounds__(BLKT, 4) void edgeconv_kernel(
    const float4* __restrict__ xq,    // (B, N) packed points
    const float* __restrict__ Wm,     // (64, 6)
    const float* __restrict__ gamma,
    const float* __restrict__ beta,
    const float* __restrict__ mean,
    const float* __restrict__ var,
    float* __restrict__ out)          // (B, 64, N)
{
    const int bid = blockIdx.x;
    const int b   = bid >> 9;                    // 512 blocks per batch
    const int n0  = (bid & 511) * QBLK;
    const int t    = threadIdx.x;
    const int lane = t & 63;
    const int w    = t >> 6;

    __shared__ unsigned long long pool[QBLK * PCAP];    // 8 KB, wave-private rows
    __shared__ int cnt[QBLK];

    const float4* xqb = xq + (size_t)b * NPTS;

    // own wave's counters only; same-wave DS ops are in-order -> no barrier
    if (lane < QPW) cnt[QPW * w + lane] = 0;

    // ---- query constants (uniform -> scalar loads) ----
    const int na = __builtin_amdgcn_readfirstlane(n0 + QPW * w);
    float q0[QPW], q1[QPW], q2[QPW];
    #pragma unroll
    for (int q = 0; q < QPW; ++q) {
        const float4 pv = xqb[na + q];
        q0[q] = 2.f * pv.x; q1[q] = 2.f * pv.y; q2[q] = 2.f * pv.z;
    }

    // ---- max pass: 2048-candidate sample, 2 lane-maxima groups per query ----
    float vm0[QPW], vm1[QPW];
    #pragma unroll
    for (int q = 0; q < QPW; ++q) { vm0[q] = -INFINITY; vm1[q] = -INFINITY; }
    #pragma unroll
    for (int g = 0; g < MITER; ++g) {                   // 8 iters of 4 loads
        float4 cc[4];
        #pragma unroll
        for (int u = 0; u < 4; ++u) cc[u] = xqb[(g * 4 + u) * 64 + lane];
        #pragma unroll
        for (int u = 0; u < 4; ++u) {
            #pragma unroll
            for (int q = 0; q < QPW; ++q) {
                const float e = fmaf(q0[q], cc[u].x, fmaf(q1[q], cc[u].y, fmaf(q2[q], cc[u].z, cc[u].w)));
                if (g < MITER / 2) vm0[q] = fmaxf(vm0[q], e);
                else               vm1[q] = fmaxf(vm1[q], e);
            }
        }
    }

    // ---- T[q] ~ 20th-largest of 128 group maxima (16-bit ballot bsearch) ----
    // The 20 top group-maxima are 20 distinct candidates >= T, so the true
    // 20th-best >= T => {all candidates >= T} is a superset of the exact
    // top-20. 16-bit truncation only lowers T (safe, slightly larger pool).
    // INTERLEAVED: rolled bit loop, 4 queries unrolled inside -> 4
    // independent ballot chains in flight.
    unsigned h0[QPW], h1[QPW], Kt[QPW];
    #pragma unroll
    for (int q = 0; q < QPW; ++q) {
        h0[q] = ord32(vm0[q]) >> 16;
        h1[q] = ord32(vm1[q]) >> 16;
        Kt[q] = 0;
    }
    #pragma unroll 1
    for (int bit = 15; bit >= 0; --bit) {
        #pragma unroll
        for (int q = 0; q < QPW; ++q) {
            const unsigned p = Kt[q] | (1u << bit);
            const int c = __popcll(__ballot(h0[q] >= p)) + __popcll(__ballot(h1[q] >= p));
            if (c >= KNN) Kt[q] = p;
        }
    }
    float Tf[QPW];
    #pragma unroll
    for (int q = 0; q < QPW; ++q) Tf[q] = iord32(Kt[q] << 16);

    const int invl = (NPTS - 1) - lane;

    // ---- filter pass: all 4096 candidates, fused filter+append ----
    #pragma unroll
    for (int g = 0; g < NPTS / 256; ++g) {              // 16 iters of 4 loads
        float4 cc[4];
        #pragma unroll
        for (int u = 0; u < 4; ++u) cc[u] = xqb[(g * 4 + u) * 64 + lane];
        #pragma unroll
        for (int u = 0; u < 4; ++u) {
            const unsigned tag = (unsigned)(invl - (g * 4 + u) * 64);
            #pragma unroll
            for (int q = 0; q < QPW; ++q) {
                const float e = fmaf(q0[q], cc[u].x, fmaf(q1[q], cc[u].y, fmaf(q2[q], cc[u].z, cc[u].w)));
                if (e >= Tf[q]) {
                    const int pos = atomicAdd(&cnt[QPW * w + q], 1);
                    if (pos < PCAP)
                        pool[(QPW * w + q) * PCAP + pos] =
                            ((unsigned long long)ord32(e) << 32) | tag;
                }
            }
        }
    }

    // ---- exact top-20 set per query: 32-bit ballot bsearch, 2 entries/lane ----
    // Wave-private pool; same-wave DS ops are in-order -> no barrier needed.
    // INTERLEAVED: per-q loads, then one rolled bit loop with the 4 query
    // chains unrolled inside.
    unsigned k0[QPW], k1[QPW], t0v[QPW], t1v[QPW], Ks[QPW];
    #pragma unroll
    for (int q = 0; q < QPW; ++q) {
        const int pr = QPW * w + q;
        const unsigned long long* pl = pool + (size_t)pr * PCAP;
        int cw = __builtin_amdgcn_readfirstlane(cnt[pr]);
        if (cw > PCAP) cw = PCAP;                      // >= 20 guaranteed
        // sentinel 0: ord32(finite) >= 1, so pad entries never counted
        const unsigned long long e0 = (lane < cw) ? pl[lane] : 0ull;
        const unsigned long long e1 = (lane + 64 < cw) ? pl[lane + 64] : 0ull;
        k0[q] = (unsigned)(e0 >> 32); t0v[q] = (unsigned)e0;
        k1[q] = (unsigned)(e1 >> 32); t1v[q] = (unsigned)e1;
        Ks[q] = 0;
    }
    #pragma unroll 1
    for (int bit = 31; bit >= 0; --bit) {
        #pragma unroll
        for (int q = 0; q < QPW; ++q) {
            const unsigned p = Ks[q] | (1u << bit);
            const int c = __popcll(__ballot(k0[q] >= p)) + __popcll(__ballot(k1[q] >= p));
            if (c >= KNN) Ks[q] = p;
        }
    }

    unsigned myidx[QPW];
    #pragma unroll
    for (int q = 0; q < QPW; ++q) {
        const unsigned K = Ks[q];
        const unsigned t0 = t0v[q], t1 = t1v[q];
        unsigned long long g0 = __ballot(k0[q] > K);
        unsigned long long g1 = __ballot(k1[q] > K);
        const int m = __popcll(g0) + __popcll(g1);     // <= 19
        unsigned long long s0 = __ballot(k0[q] == K);
        unsigned long long s1 = __ballot(k1[q] == K);
        const int r = KNN - m;                         // >= 1 ties needed
        if (__popcll(s0) + __popcll(s1) > r) {
            // tie split: choose r ties with largest tag (= lowest index)
            unsigned TT = 0;
            #pragma unroll
            for (int bit = 11; bit >= 0; --bit) {      // tags < 4096
                const unsigned p = TT | (1u << bit);
                const int c = __popcll(__ballot(k0[q] == K && t0 >= p)) +
                              __popcll(__ballot(k1[q] == K && t1 >= p));
                if (c >= r) TT = p;
            }
            s0 = __ballot(k0[q] == K && t0 >= TT);
            s1 = __ballot(k1[q] == K && t1 >= TT);
        }

        unsigned* idxq = (unsigned*)(pool + (size_t)(QPW * w + q) * PCAP); // alias own (consumed) pool
        if ((g0 >> lane) & 1) idxq[mbcnt64(g0)] = t0;
        if ((g1 >> lane) & 1) idxq[__popcll(g0) + mbcnt64(g1)] = t1;
        if ((s0 >> lane) & 1) idxq[m + mbcnt64(s0)] = t0;
        if ((s1 >> lane) & 1) idxq[m + __popcll(s0) + mbcnt64(s1)] = t1;
        myidx[q] = idxq[(lane < KNN) ? lane : 0];
    }

    // ---- epilogue: lane = output channel; neighbors via scalar loads ----
    const int o = lane;
    const float iv   = gamma[o] / sqrtf(var[o] + 1e-5f);
    const float bias = beta[o] - mean[o] * iv;
    const float* Wr = Wm + o * 6;
    const float w0p = Wr[0] * iv, w1p = Wr[1] * iv, w2p = Wr[2] * iv;
    const float w3p = Wr[3] * iv, w4p = Wr[4] * iv, w5p = Wr[5] * iv;

    float bests[QPW];
    #pragma unroll
    for (int q = 0; q < QPW; ++q) {
        const float4 pv = xqb[na + q];                 // scalar reload
        const float basep = fmaf(w3p, pv.x, fmaf(w4p, pv.y, fmaf(w5p, pv.z, bias)));
        const float base2 = basep - fmaf(w0p, pv.x, fmaf(w1p, pv.y, w2p * pv.z));
        float best = -INFINITY;
        #pragma unroll
        for (int k = 0; k < KNN; ++k) {
            const int lk = __builtin_amdgcn_readlane((int)myidx[q], k);
            const int gi = __builtin_amdgcn_readfirstlane((NPTS - 1) - lk);
            const float4 f = xqb[gi];                  // s_load_dwordx4
            float y = fmaf(w0p, f.x, fmaf(w1p, f.y, fmaf(w2p, f.z, base2)));
            y = fmaxf(y, 0.2f * y);                    // LeakyReLU
            best = fmaxf(best, y);
        }
        bests[q] = best;
    }

    // ---- direct store: lane o writes its 4 consecutive n's as one float4 ----
    float4 res;
    res.x = bests[0]; res.y = bests[1]; res.z = bests[2]; res.w = bests[3];
    *(float4*)(out + ((size_t)b * NOUT + o) * NPTS + na) = res;
}

extern "C" void kernel_launch(void* const* d_in, const int* in_sizes, int n_in,
                              void* d_out, int out_size, void* d_ws, size_t ws_size,
                              hipStream_t stream) {
    const float* x     = (const float*)d_in[0];
    const float* Wm    = (const float*)d_in[1];
    const float* gamma = (const float*)d_in[2];
    const float* beta  = (const float*)d_in[3];
    const float* mean  = (const float*)d_in[4];
    const float* var   = (const float*)d_in[5];
    float* out = (float*)d_out;
    float4* xq = (float4*)d_ws;                    // B*NPTS float4 = 512 KB

    const int B = in_sizes[0] / (3 * NPTS);        // 8
    pack_kernel<<<B * NPTS / 256, 256, 0, stream>>>(x, xq);
    const int nblocks = B * (NPTS / QBLK);         // 8 * 512 = 4096
    edgeconv_kernel<<<nblocks, BLKT, 0, stream>>>(xq, Wm, gamma, beta, mean, var, out);
}